// Round 11
// baseline (363.395 us; speedup 1.0000x reference)
//
#include <hip/hip_runtime.h>
#include <math.h>

#define B_ 8
#define T_ 2048
#define D_ 2048
#define H_ 128
#define M_ (B_ * T_)

typedef __bf16 bf16x8 __attribute__((ext_vector_type(8)));
typedef __bf16 bf16x4 __attribute__((ext_vector_type(4)));
typedef float f32x4 __attribute__((ext_vector_type(4)));

#define MFMA(a, b, c) __builtin_amdgcn_mfma_f32_16x16x32_bf16(a, b, c, 0, 0, 0)

// ws layout (bf16 elements)
#define QH_OFF 0
#define QL_OFF (1 * 2097152)  // M_*H_
#define KH_OFF (2 * 2097152)
#define KL_OFF (3 * 2097152)
#define VT_OFF (4 * 2097152)        // vt[b][h][t]
#define WTH_OFF (5 * 2097152)       // wpk_hi[g][ks][lane][8] fragment-packed
#define WTL_OFF (WTH_OFF + 786432)  // 3*128*2048

// global_load_lds: per-lane global src, wave-uniform LDS dst, 16B/lane
#define GL_LDS16(gp, lp)                                      \
  __builtin_amdgcn_global_load_lds(                           \
      (const __attribute__((address_space(1))) void*)(gp),    \
      (__attribute__((address_space(3))) void*)(lp), 16, 0, 0)

// ---------------- prep: W[k][n] fp32 -> fragment-packed hi/lo bf16 ---------
// (round-7 version, verified correct.) Packed layout: n-group g = n>>4
// (24 groups), kstep s: the 64-lane B-fragment is contiguous at elem
// ((g*64+s)*64 + lane)*8, lane = quad*16+l15, holding wt[16g+l15][32s+8q+j].
__global__ __launch_bounds__(256) void prep_kernel(
    const float* __restrict__ Wq, const float* __restrict__ Wk,
    const float* __restrict__ Wv, __bf16* __restrict__ wpk_hi,
    __bf16* __restrict__ wpk_lo) {
  const int z = blockIdx.y;
  const int k0 = blockIdx.x * 64;
  const float* W = z == 0 ? Wq : z == 1 ? Wk : Wv;
  __shared__ float tile[64][132];
  const int t = threadIdx.x;
#pragma unroll
  for (int it = 0; it < 8; ++it) {
    int f4 = it * 256 + t;  // 2048 float4 = 64 rows x 32
    int row = f4 >> 5, c = (f4 & 31) << 2;
    *(float4*)&tile[row][c] = *(const float4*)&W[(size_t)(k0 + row) * H_ + c];
  }
  __syncthreads();
  int n = t >> 1, kh = (t & 1) << 5;  // row n (0..127), k-base k0+kh
  __bf16 h[32], l[32];
#pragma unroll
  for (int kk = 0; kk < 32; ++kk) {
    float x = tile[kh + kk][n];
    __bf16 hi = (__bf16)x;
    h[kk] = hi;
    l[kk] = (__bf16)(x - (float)hi);
  }
  const int nf = z * H_ + n;  // 0..383
  const int g = nf >> 4, l15 = nf & 15;
  const int s = (k0 + kh) >> 5;
#pragma unroll
  for (int c = 0; c < 4; ++c) {  // chunk c -> quad c
    size_t dst = ((size_t)(g * 64 + s) * 64 + c * 16 + l15) * 8;
    *(bf16x8*)&wpk_hi[dst] = *(bf16x8*)&h[c * 8];
    *(bf16x8*)&wpk_lo[dst] = *(bf16x8*)&l[c * 8];
  }
}

// ---------------- proj: T3 2-phase, gload_lds W, dbuf LDS, 1 barrier/kstep -
// v8 (round-9, verified 117us): 512 blocks x 512 thr (8 waves). Block =
// 64m x 192n (n-half = bi&1 -> XCD parity, W-half L2-resident). Wave =
// 32m x 48n, 18 MFMA/kstep. W staged by global_load_lds (width 16, 3/wave/
// kstep, zero ds_writes, zero repack) from the packed layout into lane-
// linear LDS fragments (conflict-free b128 reads); X+W double-buffered;
// ONE raw s_barrier per kstep with counted vmcnt(1) that never drains the
// depth-2 X register prefetch (xA/xB static names, rule #20).
// Round-9 PMC: MfmaUtil 23->27, conflicts halved, dur 132->117.
#define XSTR 72  // X row-pair stride (32 hi | 32 lo | 8 pad) = 144 B

#define XCONV(RW, NB)                                                       \
  {                                                                         \
    __bf16 h0 = (__bf16)RW.x, h1 = (__bf16)RW.y, h2 = (__bf16)RW.z,         \
           h3 = (__bf16)RW.w;                                               \
    bf16x4 hv = {h0, h1, h2, h3};                                           \
    bf16x4 lv = {(__bf16)(RW.x - (float)h0), (__bf16)(RW.y - (float)h1),    \
                 (__bf16)(RW.z - (float)h2), (__bf16)(RW.w - (float)h3)};   \
    *(bf16x4*)&Xs[NB][xm * XSTR + xk] = hv;                                 \
    *(bf16x4*)&Xs[NB][xm * XSTR + 32 + xk] = lv;                            \
  }

#define COMPUTE(CUR)                                                        \
  {                                                                         \
    bf16x8 ah[2], al[2];                                                    \
    _Pragma("unroll") for (int mg = 0; mg < 2; ++mg) {                      \
      ah[mg] = *(bf16x8*)&Xs[CUR][(wr * 32 + mg * 16 + l15) * XSTR + q8];   \
      al[mg] =                                                              \
          *(bf16x8*)&Xs[CUR][(wr * 32 + mg * 16 + l15) * XSTR + 32 + q8];   \
    }                                                                       \
    _Pragma("unroll") for (int nt = 0; nt < 3; ++nt) {                      \
      const int g = wc * 3 + nt;                                            \
      bf16x8 bh = *(bf16x8*)&Wf[CUR][g * 512 + lane * 8];                   \
      bf16x8 bl = *(bf16x8*)&Wf[CUR][6144 + g * 512 + lane * 8];            \
      _Pragma("unroll") for (int mg = 0; mg < 2; ++mg) {                    \
        acc[mg][nt] = MFMA(ah[mg], bh, acc[mg][nt]);                        \
        acc[mg][nt] = MFMA(al[mg], bh, acc[mg][nt]);                        \
        acc[mg][nt] = MFMA(ah[mg], bl, acc[mg][nt]);                        \
      }                                                                     \
    }                                                                       \
  }

#define PSTEP(KS, RW, RL)                                                   \
  {                                                                         \
    const int nb_ = ((KS)&1) ^ 1;                                           \
    _Pragma("unroll") for (int i = 0; i < 3; ++i)                           \
        GL_LDS16(gsrc[i] + ((KS) + 1) * 512, ldst0[i] + nb_ * 12288);       \
    __builtin_amdgcn_sched_barrier(0); /* gloads older than X load */       \
    RL = *(const float4*)(xgp + ((KS) + 2) * 32);                           \
    XCONV(RW, nb_);                                                         \
    COMPUTE((KS)&1);                                                        \
    asm volatile("s_waitcnt vmcnt(1) lgkmcnt(0)" ::: "memory");             \
    __builtin_amdgcn_sched_barrier(0);                                      \
    __builtin_amdgcn_s_barrier();                                           \
    __builtin_amdgcn_sched_barrier(0);                                      \
  }

__global__ __launch_bounds__(512, 4) void proj_kernel(
    const float* __restrict__ X, const __bf16* __restrict__ wpk_hi,
    const __bf16* __restrict__ wpk_lo, __bf16* __restrict__ qh,
    __bf16* __restrict__ ql, __bf16* __restrict__ kh,
    __bf16* __restrict__ kl, __bf16* __restrict__ vt) {
  __shared__ __align__(16) __bf16 Wf[2][12288];      // 49152 B (dbuf frags)
  __shared__ __align__(16) __bf16 Xs[2][64 * XSTR];  // 18432 B (dbuf)
  const int t = threadIdx.x;
  const int wv = t >> 6, lane = t & 63;
  const int l15 = lane & 15, quad = lane >> 4, q8 = quad * 8;
  const int bi = blockIdx.x;
  const int m0 = (bi >> 1) * 64;
  const int nbase = (bi & 1) * 192;
  const int wr = wv >> 2, wc = wv & 3;  // wave tile: 32m x 48n
  // X staging map: 64 rows x 8 col-quads (one float4/thread)
  const int xm = t >> 3, xk = (t & 7) << 2;
  const float* xgp = X + (size_t)(m0 + xm) * D_ + xk;
  // W staging: wave wv owns fragments f = wv*3 + i, f in [0,24):
  // sel = f/12 (hi|lo), gl = f%12; global group gg = nbase/16 + gl.
  const __bf16* gsrc[3];
  __bf16* ldst0[3];
#pragma unroll
  for (int i = 0; i < 3; ++i) {
    int f = wv * 3 + i;
    int sel = f >= 12;
    int gl = f - sel * 12;
    int gg = (nbase >> 4) + gl;
    gsrc[i] = (sel ? wpk_lo : wpk_hi) + (size_t)gg * 32768 + (size_t)lane * 8;
    ldst0[i] = &Wf[0][sel * 6144 + gl * 512];
  }
  f32x4 acc[2][3] = {};
  // prologue: stage kstep 0 (W via gload_lds, X via reg+convert), load X(1)
  {
    float4 x0 = *(const float4*)xgp;
#pragma unroll
    for (int i = 0; i < 3; ++i) GL_LDS16(gsrc[i], ldst0[i]);
    XCONV(x0, 0);
  }
  float4 xA = *(const float4*)(xgp + 32);  // X(1)
  float4 xB;
  asm volatile("s_waitcnt vmcnt(0) lgkmcnt(0)" ::: "memory");
  __builtin_amdgcn_sched_barrier(0);
  __builtin_amdgcn_s_barrier();
  __builtin_amdgcn_sched_barrier(0);
  // main loop: ks = 0..61 (paired for static xA/xB renaming)
  for (int ks2 = 0; ks2 < 62; ks2 += 2) {
    PSTEP(ks2, xA, xB);
    PSTEP(ks2 + 1, xB, xA);
  }
  // ks = 62: stage W(63) + X(63); no further X load -> full drain
  {
#pragma unroll
    for (int i = 0; i < 3; ++i)
      GL_LDS16(gsrc[i] + 63 * 512, ldst0[i] + 12288);
    XCONV(xA, 1);
    COMPUTE(0);
    asm volatile("s_waitcnt vmcnt(0) lgkmcnt(0)" ::: "memory");
    __builtin_amdgcn_sched_barrier(0);
    __builtin_amdgcn_s_barrier();
    __builtin_amdgcn_sched_barrier(0);
  }
  COMPUTE(1);  // ks = 63
  // epilogue (C/D: col = l15 -> n, row = quad*4+reg -> m)
#pragma unroll
  for (int nt = 0; nt < 3; ++nt) {
    int ncb = nbase + wc * 48 + nt * 16;  // 16-aligned, within one z
    int z = ncb >> 7;
    int h = (ncb & 127) + l15;
#pragma unroll
    for (int mg = 0; mg < 2; ++mg) {
      int r0 = m0 + wr * 32 + mg * 16 + quad * 4;
      if (z == 2) {
        int b = m0 >> 11;
        int tt0 = (m0 & 2047) + wr * 32 + mg * 16 + quad * 4;
        bf16x4 pv = {(__bf16)acc[mg][nt][0], (__bf16)acc[mg][nt][1],
                     (__bf16)acc[mg][nt][2], (__bf16)acc[mg][nt][3]};
        *(bf16x4*)&vt[(size_t)(b * H_ + h) * T_ + tt0] = pv;
      } else {
        __bf16* dh = z == 0 ? qh : kh;
        __bf16* dl = z == 0 ? ql : kl;
#pragma unroll
        for (int reg = 0; reg < 4; ++reg) {
          float v = acc[mg][nt][reg];
          __bf16 hi = (__bf16)v;
          dh[(size_t)(r0 + reg) * H_ + h] = hi;
          dl[(size_t)(r0 + reg) * H_ + h] = (__bf16)(v - (float)hi);
        }
      }
    }
  }
}

// ---------------- attention: flash, split-bf16 QK (3-pass), bf16 PV --------
// round-0 structure (two complementary q-halves per block: st=0 -> pi,
// st=1 -> 63-pi, 4 waves each -- balance is INTRA-block, scheduler-proof).
// block mapping b=j&7, pi=j>>3 gives batch<->XCD affinity (verified round
// 1: FETCH 51MB -> 10.6MB).
// v10 change: __launch_bounds__(512, 1). The old (512,2) capped VGPR at
// 128 (measured 124) while live state is ~200 (qfh/qfl 64 + O 64 + S 32 +
// frags/temps) -> compiler spilled ~70 regs; every k-tile touched all of
// O and Q, so per-tile time was ~18us vs ~2us of real dataflow with every
// pipe <10% busy. (512,1) allows 256 VGPR/wave (8 waves = 2/SIMD fits the
// VGPR file); grid is 256 = 1 block/CU anyway, so nothing is lost.
__global__ __launch_bounds__(512, 1) void attn_kernel(
    const __bf16* __restrict__ qh, const __bf16* __restrict__ qlo,
    const __bf16* __restrict__ kh, const __bf16* __restrict__ klo,
    const __bf16* __restrict__ vt, float* __restrict__ out) {
  const int t = threadIdx.x;
  const int wv = t >> 6, st = wv >> 2, cw = wv & 3;
  const int lane = t & 63, l15 = lane & 15, quad = lane >> 4;
  const int j = blockIdx.x, b = j & 7, pi = j >> 3;
  const int qlidx = (st == 0) ? pi : 63 - pi;
  const int t0 = qlidx * 32;
  const int nkt = (qlidx >> 1) + 1;
  __shared__ __align__(16) __bf16 Pbuf[8][32 * 72];
  __shared__ __align__(16) float Obuf[2][32 * 132];
  __shared__ float mlb[2][4][32], llb[2][4][32];
  const size_t qrow0 = (size_t)b * T_ + t0;
  bf16x8 qfh[2][4], qfl[2][4];
#pragma unroll
  for (int mg = 0; mg < 2; ++mg)
#pragma unroll
    for (int ds = 0; ds < 4; ++ds) {
      size_t off = (qrow0 + mg * 16 + l15) * H_ + ds * 32 + quad * 8;
      qfh[mg][ds] = *(const bf16x8*)(qh + off);
      qfl[mg][ds] = *(const bf16x8*)(qlo + off);
    }
  f32x4 O[2][8] = {};
  float ms[2][4], ls[2][4];
#pragma unroll
  for (int mg = 0; mg < 2; ++mg)
#pragma unroll
    for (int reg = 0; reg < 4; ++reg) {
      ms[mg][reg] = -INFINITY;
      ls[mg][reg] = 0.f;
    }
  const __bf16* vtb = vt + (size_t)b * H_ * T_;
  const float scale = 11.313708498984761f;  // sqrt(128); ref multiplies
  for (int kt_i = cw; kt_i < nkt; kt_i += 4) {
    const int kt = kt_i * 64;
    f32x4 S[2][4] = {};
#pragma unroll
    for (int ds = 0; ds < 4; ++ds)
#pragma unroll
      for (int ct = 0; ct < 4; ++ct) {
        size_t koff =
            ((size_t)b * T_ + kt + ct * 16 + l15) * H_ + ds * 32 + quad * 8;
        bf16x8 bh = *(const bf16x8*)(kh + koff);
        bf16x8 bl = *(const bf16x8*)(klo + koff);
#pragma unroll
        for (int mg = 0; mg < 2; ++mg) {
          S[mg][ct] = MFMA(qfh[mg][ds], bh, S[mg][ct]);
          S[mg][ct] = MFMA(qfl[mg][ds], bh, S[mg][ct]);
          S[mg][ct] = MFMA(qfh[mg][ds], bl, S[mg][ct]);
        }
      }
    const bool diag = (kt_i == nkt - 1);
#pragma unroll
    for (int mg = 0; mg < 2; ++mg)
#pragma unroll
      for (int ct = 0; ct < 4; ++ct)
#pragma unroll
        for (int reg = 0; reg < 4; ++reg) {
          float s = S[mg][ct][reg] * scale;
          if (diag && (kt + ct * 16 + l15 > t0 + mg * 16 + quad * 4 + reg))
            s = -1e30f;
          S[mg][ct][reg] = s;
        }
    float al_[2][4];
#pragma unroll
    for (int mg = 0; mg < 2; ++mg)
#pragma unroll
      for (int reg = 0; reg < 4; ++reg) {
        float r = fmaxf(fmaxf(S[mg][0][reg], S[mg][1][reg]),
                        fmaxf(S[mg][2][reg], S[mg][3][reg]));
        r = fmaxf(r, __shfl_xor(r, 1));
        r = fmaxf(r, __shfl_xor(r, 2));
        r = fmaxf(r, __shfl_xor(r, 4));
        r = fmaxf(r, __shfl_xor(r, 8));
        float mn = fmaxf(ms[mg][reg], r);
        float a = __expf(ms[mg][reg] - mn);
        ms[mg][reg] = mn;
        float ps = 0.f;
#pragma unroll
        for (int ct = 0; ct < 4; ++ct) {
          float p = __expf(S[mg][ct][reg] - mn);
          S[mg][ct][reg] = p;
          ps += p;
        }
        ps += __shfl_xor(ps, 1);
        ps += __shfl_xor(ps, 2);
        ps += __shfl_xor(ps, 4);
        ps += __shfl_xor(ps, 8);
        ls[mg][reg] = ls[mg][reg] * a + ps;
        al_[mg][reg] = a;
      }
#pragma unroll
    for (int mg = 0; mg < 2; ++mg)
#pragma unroll
      for (int ht = 0; ht < 8; ++ht)
#pragma unroll
        for (int reg = 0; reg < 4; ++reg) O[mg][ht][reg] *= al_[mg][reg];
#pragma unroll
    for (int mg = 0; mg < 2; ++mg)
#pragma unroll
      for (int ct = 0; ct < 4; ++ct)
#pragma unroll
        for (int reg = 0; reg < 4; ++reg)
          Pbuf[wv][(mg * 16 + quad * 4 + reg) * 72 + ct * 16 + l15] =
              (__bf16)S[mg][ct][reg];
#pragma unroll
    for (int ks = 0; ks < 2; ++ks) {
      bf16x8 pf0 = *(bf16x8*)&Pbuf[wv][(l15)*72 + ks * 32 + quad * 8];
      bf16x8 pf1 = *(bf16x8*)&Pbuf[wv][(16 + l15) * 72 + ks * 32 + quad * 8];
#pragma unroll
      for (int ht = 0; ht < 8; ++ht) {
        bf16x8 vf = *(const bf16x8*)&vtb[(size_t)(ht * 16 + l15) * T_ + kt +
                                         ks * 32 + quad * 8];
        O[0][ht] = MFMA(pf0, vf, O[0][ht]);
        O[1][ht] = MFMA(pf1, vf, O[1][ht]);
      }
    }
  }
  if (l15 == 0) {
#pragma unroll
    for (int mg = 0; mg < 2; ++mg)
#pragma unroll
      for (int reg = 0; reg < 4; ++reg) {
        mlb[st][cw][mg * 16 + quad * 4 + reg] = ms[mg][reg];
        llb[st][cw][mg * 16 + quad * 4 + reg] = ls[mg][reg];
      }
  }
  for (int i = t; i < 2 * 32 * 132; i += 512) ((float*)Obuf)[i] = 0.f;
  __syncthreads();
  float aw[2][4];
#pragma unroll
  for (int mg = 0; mg < 2; ++mg)
#pragma unroll
    for (int reg = 0; reg < 4; ++reg) {
      int row = mg * 16 + quad * 4 + reg;
      float M = fmaxf(fmaxf(mlb[st][0][row], mlb[st][1][row]),
                      fmaxf(mlb[st][2][row], mlb[st][3][row]));
      float L = 0.f;
#pragma unroll
      for (int w = 0; w < 4; ++w)
        L += llb[st][w][row] * __expf(mlb[st][w][row] - M);
      aw[mg][reg] = __expf(ms[mg][reg] - M) / L;
    }
#pragma unroll
  for (int mg = 0; mg < 2; ++mg)
#pragma unroll
    for (int ht = 0; ht < 8; ++ht)
#pragma unroll
      for (int reg = 0; reg < 4; ++reg)
        atomicAdd(&Obuf[st][(mg * 16 + quad * 4 + reg) * 132 + ht * 16 + l15],
                  O[mg][ht][reg] * aw[mg][reg]);
  __syncthreads();
  {
    const int stw = t >> 8, tt = t & 255;
    const int qlw = (stw == 0) ? pi : 63 - pi;
    const size_t obase = ((size_t)b * T_ + qlw * 32) * H_;
#pragma unroll
    for (int i = 0; i < 4; ++i) {
      int f4 = i * 256 + tt;
      int row = f4 >> 5, c = (f4 & 31) << 2;
      *(float4*)&out[obase + (size_t)row * H_ + c] =
          *(float4*)&Obuf[stw][row * 132 + c];
    }
  }
}

extern "C" void kernel_launch(void* const* d_in, const int* in_sizes, int n_in,
                              void* d_out, int out_size, void* d_ws, size_t ws_size,
                              hipStream_t stream) {
  const float* x = (const float*)d_in[0];
  const float* Wq = (const float*)d_in[1];
  const float* Wk = (const float*)d_in[2];
  const float* Wv = (const float*)d_in[3];
  __bf16* ws = (__bf16*)d_ws;
  float* out = (float*)d_out;
  prep_kernel<<<dim3(32, 3), 256, 0, stream>>>(Wq, Wk, Wv, ws + WTH_OFF,
                                               ws + WTL_OFF);
  proj_kernel<<<512, 512, 0, stream>>>(x, ws + WTH_OFF, ws + WTL_OFF,
                                       ws + QH_OFF, ws + QL_OFF, ws + KH_OFF,
                                       ws + KL_OFF, ws + VT_OFF);
  attn_kernel<<<256, 512, 0, stream>>>(ws + QH_OFF, ws + QL_OFF, ws + KH_OFF,
                                       ws + KL_OFF, ws + VT_OFF, out);
}